// Round 2
// baseline (7289.207 us; speedup 1.0000x reference)
//
#include <hip/hip_runtime.h>
#include <math.h>

#define NBATCH 4
#define NSEQ   1024
#define DHID   512
#define NHEADS 16
#define ROWS   (NBATCH*NSEQ)   /* 4096  */
#define VROWS  (ROWS*3)        /* 12288 */
#define ATT_FACTOR 0.08838834764831845f  /* 0.5/sqrt(32) */

// ---------------- LayerNorm: one block per row of 512 ----------------
__global__ __launch_bounds__(256) void ln_kernel(
    const float* __restrict__ x, float* __restrict__ y, int ystride,
    const float* __restrict__ g, const float* __restrict__ beta)
{
  int row = blockIdx.x;
  int t = threadIdx.x;
  const float* xr = x + (size_t)row * DHID;
  float2 v = ((const float2*)xr)[t];
  float s  = v.x + v.y;
  float ss = v.x*v.x + v.y*v.y;
  #pragma unroll
  for (int off = 32; off > 0; off >>= 1) {
    s  += __shfl_down(s, off);
    ss += __shfl_down(ss, off);
  }
  __shared__ float red[8];
  int w = t >> 6;
  if ((t & 63) == 0) { red[w*2] = s; red[w*2+1] = ss; }
  __syncthreads();
  s  = red[0] + red[2] + red[4] + red[6];
  ss = red[1] + red[3] + red[5] + red[7];
  float mean = s * (1.0f/DHID);
  float var  = ss * (1.0f/DHID) - mean*mean;
  float rstd = rsqrtf(var + 1e-5f);
  float2 gg = ((const float2*)g)[t];
  float2 bb = ((const float2*)beta)[t];
  float2 o;
  o.x = (v.x - mean) * rstd * gg.x + bb.x;
  o.y = (v.y - mean) * rstd * gg.y + bb.y;
  *(float2*)&y[(size_t)row * ystride + 2*t] = o;
}

// ------------- generic SGEMM: C = act(A@W + bias) + resid -------------
// BM=BN=128, BK=8, 256 threads, 8x8 per thread. M%128==0, N%128==0, K%8==0.
template<int ACT, int HAS_BIAS, int HAS_RES>
__global__ __launch_bounds__(256) void gemm_kernel(
    const float* __restrict__ A, const float* __restrict__ W,
    const float* __restrict__ bias, const float* __restrict__ resid,
    float* __restrict__ C, int M, int N, int K)
{
  __shared__ float As[8][128];
  __shared__ float Bs[8][128];
  int t  = threadIdx.x;
  int tx = t & 15, ty = t >> 4;
  int row0 = blockIdx.y * 128, col0 = blockIdx.x * 128;
  int am = t >> 1,  ak = (t & 1) * 4;
  int bk = t >> 5,  bn = (t & 31) * 4;
  const float* Ap = A + (size_t)(row0 + am) * K + ak;
  const float* Wp = W + (size_t)bk * N + col0 + bn;
  float acc[8][8] = {};
  for (int k0 = 0; k0 < K; k0 += 8) {
    float4 av = *(const float4*)Ap; Ap += 8;
    float4 bv = *(const float4*)Wp; Wp += (size_t)8 * N;
    __syncthreads();
    As[ak+0][am] = av.x; As[ak+1][am] = av.y;
    As[ak+2][am] = av.z; As[ak+3][am] = av.w;
    *(float4*)&Bs[bk][bn] = bv;
    __syncthreads();
    #pragma unroll
    for (int kk = 0; kk < 8; kk++) {
      float4 a0 = *(const float4*)&As[kk][ty*8];
      float4 a1 = *(const float4*)&As[kk][ty*8+4];
      float4 b0 = *(const float4*)&Bs[kk][tx*8];
      float4 b1 = *(const float4*)&Bs[kk][tx*8+4];
      float ar[8] = {a0.x,a0.y,a0.z,a0.w,a1.x,a1.y,a1.z,a1.w};
      float br[8] = {b0.x,b0.y,b0.z,b0.w,b1.x,b1.y,b1.z,b1.w};
      #pragma unroll
      for (int i = 0; i < 8; i++)
        #pragma unroll
        for (int j = 0; j < 8; j++)
          acc[i][j] += ar[i]*br[j];
    }
  }
  #pragma unroll
  for (int i = 0; i < 8; i++) {
    int r = row0 + ty*8 + i;
    #pragma unroll
    for (int j4 = 0; j4 < 2; j4++) {
      int c = col0 + tx*8 + j4*4;
      float4 o = { acc[i][j4*4+0], acc[i][j4*4+1], acc[i][j4*4+2], acc[i][j4*4+3] };
      if constexpr (HAS_BIAS) {
        o.x += bias[c]; o.y += bias[c+1]; o.z += bias[c+2]; o.w += bias[c+3];
      }
      if constexpr (ACT == 1) {  // SiLU
        o.x = o.x / (1.f + __expf(-o.x));
        o.y = o.y / (1.f + __expf(-o.y));
        o.z = o.z / (1.f + __expf(-o.z));
        o.w = o.w / (1.f + __expf(-o.w));
      }
      if constexpr (HAS_RES) {
        float4 rv = *(const float4*)&resid[(size_t)r*N + c];
        o.x += rv.x; o.y += rv.y; o.z += rv.z; o.w += rv.w;
      }
      *(float4*)&C[(size_t)r*N + c] = o;
    }
  }
}

// ------------- pack V_attn = [Hv | Vv head-interleaved] -------------
__global__ __launch_bounds__(256) void pack_vattn_kernel(
    const float* __restrict__ Hv, const float* __restrict__ Vvr, float* __restrict__ VA)
{
  int idx = blockIdx.x*256 + threadIdx.x;      // < ROWS*2048
  int row = idx >> 11;
  int rem = idx & 2047;
  int h = rem >> 7;
  int d = rem & 127;
  float v;
  if (d < 32) v = Hv[(size_t)row*DHID + h*32 + d];
  else { int c = (d-32) >> 5; int j = d & 31; v = Vvr[(size_t)(row*3+c)*DHID + h*32 + j]; }
  VA[idx] = v;
}

// ------------- flash attention, fp32, TQ=32 TM=32 -------------
__global__ __launch_bounds__(256) void attn_kernel(
    const float* __restrict__ Q,  const float* __restrict__ Km,
    const float* __restrict__ Va, const float* __restrict__ Db,
    const float* __restrict__ Rb, const int* __restrict__ Mask,
    float* __restrict__ Out)
{
  __shared__ float Qs[32][132];
  __shared__ float Ks[32][132];
  __shared__ float Vs[32][132];
  __shared__ float Ps[32][36];
  int t = threadIdx.x;
  int qblk = blockIdx.x & 31;
  int h = (blockIdx.x >> 5) & 15;
  int b = blockIdx.x >> 9;
  int q0 = qblk * 32;
  #pragma unroll
  for (int i = 0; i < 4; i++) {
    int f = t + i*256;
    int r = f >> 5, c4 = f & 31;
    *(float4*)&Qs[r][c4*4] =
        *(const float4*)&Q[(size_t)(b*NSEQ + q0 + r)*2048 + h*128 + c4*4];
  }
  int r = t >> 3, g8 = t & 7;
  float acc[16] = {};
  float m_i = -1e30f, l_i = 0.f;
  int q = q0 + r;
  for (int m0 = 0; m0 < NSEQ; m0 += 32) {
    __syncthreads();
    #pragma unroll
    for (int i = 0; i < 4; i++) {
      int f = t + i*256;
      int rr = f >> 5, c4 = f & 31;
      size_t gi = (size_t)(b*NSEQ + m0 + rr)*2048 + h*128 + c4*4;
      *(float4*)&Ks[rr][c4*4] = *(const float4*)&Km[gi];
      *(float4*)&Vs[rr][c4*4] = *(const float4*)&Va[gi];
    }
    __syncthreads();
    float4 sa[4] = {};
    const float4* qrow = (const float4*)&Qs[r][0];
    #pragma unroll
    for (int k4 = 0; k4 < 32; k4++) {
      float4 qv = qrow[k4];
      #pragma unroll
      for (int j = 0; j < 4; j++) {
        float4 kv = *(const float4*)&Ks[g8 + 8*j][k4*4];
        sa[j].x += qv.x*kv.x; sa[j].y += qv.y*kv.y;
        sa[j].z += qv.z*kv.z; sa[j].w += qv.w*kv.w;
      }
    }
    float s[4];
    float mx = -3e38f;
    #pragma unroll
    for (int j = 0; j < 4; j++) {
      int m = m0 + g8 + 8*j;
      int gi = (b*NSEQ + q)*NSEQ + m;
      float bb = Mask[b*NSEQ + m] ? (Db[gi] + Rb[gi]) : -1e30f;
      s[j] = (sa[j].x+sa[j].y+sa[j].z+sa[j].w)*ATT_FACTOR + bb;
      mx = fmaxf(mx, s[j]);
    }
    mx = fmaxf(mx, __shfl_xor(mx, 1));
    mx = fmaxf(mx, __shfl_xor(mx, 2));
    mx = fmaxf(mx, __shfl_xor(mx, 4));
    float m_new = fmaxf(m_i, mx);
    float alpha = __expf(m_i - m_new);
    float ps = 0.f;
    #pragma unroll
    for (int j = 0; j < 4; j++) {
      float p = __expf(s[j] - m_new);
      Ps[r][g8 + 8*j] = p;
      ps += p;
    }
    ps += __shfl_xor(ps, 1); ps += __shfl_xor(ps, 2); ps += __shfl_xor(ps, 4);
    l_i = l_i * alpha + ps;
    m_i = m_new;
    #pragma unroll
    for (int d = 0; d < 16; d++) acc[d] *= alpha;
    __syncthreads();
    #pragma unroll 4
    for (int mm = 0; mm < 32; mm++) {
      float p = Ps[r][mm];
      #pragma unroll
      for (int ii = 0; ii < 4; ii++) {
        float4 v = *(const float4*)&Vs[mm][(g8 + 8*ii)*4];
        acc[ii*4+0] += p*v.x; acc[ii*4+1] += p*v.y;
        acc[ii*4+2] += p*v.z; acc[ii*4+3] += p*v.w;
      }
    }
  }
  float inv = 1.0f / l_i;
  size_t ob = (size_t)((b*NSEQ + q0 + r)*16 + h) * 128;
  #pragma unroll
  for (int ii = 0; ii < 4; ii++) {
    float4 o = { acc[ii*4]*inv, acc[ii*4+1]*inv, acc[ii*4+2]*inv, acc[ii*4+3]*inv };
    *(float4*)&Out[ob + (g8 + 8*ii)*4] = o;
  }
}

// ------------- unpack attention result into H_res / V_res -------------
__global__ __launch_bounds__(256) void pack_hres_kernel(
    const float* __restrict__ RES, float* __restrict__ HRES)
{
  int idx = blockIdx.x*256 + threadIdx.x;   // < ROWS*512
  int row = idx >> 9;
  int col = idx & 511;
  int h = col >> 5, j = col & 31;
  HRES[idx] = RES[(size_t)(row*16 + h)*128 + j];
}

__global__ __launch_bounds__(256) void pack_vres_kernel(
    const float* __restrict__ RES, float* __restrict__ VRES)
{
  int idx = blockIdx.x*256 + threadIdx.x;   // < VROWS*512
  int r3 = idx >> 9;
  int col = idx & 511;
  int h = col >> 5, j = col & 31;
  int row = r3 / 3, c = r3 - row*3;
  VRES[idx] = RES[(size_t)(row*16 + h)*128 + 32 + c*32 + j];
}

// ------------- scaler second half: ||V1||_2 over the 3 axis -------------
__global__ __launch_bounds__(256) void vnorm_kernel(
    const float* __restrict__ VP, float* __restrict__ SC)
{
  int idx = blockIdx.x*256 + threadIdx.x;   // < ROWS*512
  int row = idx >> 9;
  int d = idx & 511;
  const float* p = VP + (size_t)row*3072 + d;
  float a = p[0], b = p[1024], c = p[2048];
  SC[(size_t)row*1024 + 512 + d] = sqrtf(a*a + b*b + c*c);
}

// ------------- final combines -------------
__global__ __launch_bounds__(256) void addh_kernel(
    const float* __restrict__ HH, float* __restrict__ Hout)
{
  int idx = blockIdx.x*256 + threadIdx.x;   // < ROWS*512
  int row = idx >> 9;
  int d = idx & 511;
  Hout[idx] += HH[(size_t)row*1024 + d];
}

__global__ __launch_bounds__(256) void fmav_kernel(
    const float* __restrict__ HH, const float* __restrict__ VP, float* __restrict__ Vout)
{
  int idx = blockIdx.x*256 + threadIdx.x;   // < VROWS*512
  int r3 = idx >> 9;
  int d = idx & 511;
  int row = r3 / 3;
  Vout[idx] += HH[(size_t)row*1024 + 512 + d] * VP[(size_t)r3*1024 + 512 + d];
}

extern "C" void kernel_launch(void* const* d_in, const int* in_sizes, int n_in,
                              void* d_out, int out_size, void* d_ws, size_t ws_size,
                              hipStream_t stream)
{
  const float* H    = (const float*)d_in[0];
  const float* V    = (const float*)d_in[1];
  const float* Db   = (const float*)d_in[2];
  const float* Rb   = (const float*)d_in[3];
  const int*   Mask = (const int*)d_in[4];
  const float* g1   = (const float*)d_in[5];
  const float* be1  = (const float*)d_in[6];
  const float* Wq   = (const float*)d_in[7];
  const float* bq   = (const float*)d_in[8];
  const float* Wk   = (const float*)d_in[9];
  const float* bkk  = (const float*)d_in[10];
  const float* Wv   = (const float*)d_in[11];
  const float* bv   = (const float*)d_in[12];
  const float* Wvv  = (const float*)d_in[13];
  const float* Wo   = (const float*)d_in[14];
  const float* bo   = (const float*)d_in[15];
  const float* Wvo  = (const float*)d_in[16];
  const float* g2   = (const float*)d_in[17];
  const float* be2  = (const float*)d_in[18];
  const float* Wlv  = (const float*)d_in[19];
  const float* W1   = (const float*)d_in[20];
  const float* b1f  = (const float*)d_in[21];
  const float* W2   = (const float*)d_in[22];
  const float* b2f  = (const float*)d_in[23];

  float* Hout = (float*)d_out;                  // 4096 x 512
  float* Vout = Hout + (size_t)ROWS*DHID;       // 12288 x 512

  char* w = (char*)d_ws;
  const size_t MB = 1024*1024;
  // phase 1 regions
  float* HN   = (float*)(w + 0);        //  8MB  Hn
  float* Qb   = (float*)(w + 8*MB);     // 32MB  Q
  float* Kb   = (float*)(w + 40*MB);    // 32MB  K
  float* VA   = (float*)(w + 72*MB);    // 32MB  packed V_attn
  float* VVr  = (float*)(w + 104*MB);   // 24MB  V@Wvv raw
  float* HVt  = (float*)(w + 128*MB);   //  8MB  Hn@Wv
  float* RES  = (float*)(w + 104*MB);   // 32MB  attention out (reuses VVr/HVt)
  // phase 2 regions (after attention / projections)
  float* HRES = (float*)(w + 0);        //  8MB  (reuses HN)
  float* VRES = (float*)(w + 8*MB);     // 24MB  (reuses Q)
  float* VP   = (float*)(w + 0);        // 48MB  (after Wo/Wvo gemms)
  float* SC   = (float*)(w + 48*MB);    // 16MB  scaler
  float* S1   = (float*)(w + 64*MB);    // 32MB  silu(scaler@W1+b1)
  float* HHb  = (float*)(w + 96*MB);    // 16MB  final h

  dim3 blk(256);

  ln_kernel<<<ROWS, blk, 0, stream>>>(H, HN, DHID, g1, be1);

  gemm_kernel<0,1,0><<<dim3(16, 32), blk, 0, stream>>>(HN, Wq, bq,  nullptr, Qb,  4096, 2048, 512);
  gemm_kernel<0,1,0><<<dim3(16, 32), blk, 0, stream>>>(HN, Wk, bkk, nullptr, Kb,  4096, 2048, 512);
  gemm_kernel<0,1,0><<<dim3(4,  32), blk, 0, stream>>>(HN, Wv, bv,  nullptr, HVt, 4096, 512,  512);
  gemm_kernel<0,0,0><<<dim3(4,  96), blk, 0, stream>>>(V,  Wvv, nullptr, nullptr, VVr, 12288, 512, 512);

  pack_vattn_kernel<<<(ROWS*2048)/256, blk, 0, stream>>>(HVt, VVr, VA);

  attn_kernel<<<2048, blk, 0, stream>>>(Qb, Kb, VA, Db, Rb, Mask, RES);

  pack_hres_kernel<<<(ROWS*DHID)/256,  blk, 0, stream>>>(RES, HRES);
  pack_vres_kernel<<<(VROWS*DHID)/256, blk, 0, stream>>>(RES, VRES);

  gemm_kernel<0,1,1><<<dim3(4, 32), blk, 0, stream>>>(HRES, Wo,  bo, H, Hout, 4096, 512, 512);
  gemm_kernel<0,0,1><<<dim3(4, 96), blk, 0, stream>>>(VRES, Wvo, nullptr, V, Vout, 12288, 512, 512);

  ln_kernel<<<ROWS, blk, 0, stream>>>(Hout, SC, 1024, g2, be2);
  gemm_kernel<0,0,0><<<dim3(8, 96), blk, 0, stream>>>(Vout, Wlv, nullptr, nullptr, VP, 12288, 1024, 512);
  vnorm_kernel<<<(ROWS*DHID)/256, blk, 0, stream>>>(VP, SC);

  gemm_kernel<1,1,0><<<dim3(16, 32), blk, 0, stream>>>(SC, W1, b1f, nullptr, S1,  4096, 2048, 1024);
  gemm_kernel<0,1,0><<<dim3(8,  32), blk, 0, stream>>>(S1, W2, b2f, nullptr, HHb, 4096, 1024, 2048);

  addh_kernel<<<(ROWS*DHID)/256,  blk, 0, stream>>>(HHb, Hout);
  fmav_kernel<<<(VROWS*DHID)/256, blk, 0, stream>>>(HHb, VP, Vout);
}

// Round 3
// 1652.221 us; speedup vs baseline: 4.4118x; 4.4118x over previous
//
#include <hip/hip_runtime.h>
#include <math.h>

#define NBATCH 4
#define NSEQ   1024
#define DHID   512
#define NHEADS 16
#define ROWS   (NBATCH*NSEQ)   /* 4096  */
#define VROWS  (ROWS*3)        /* 12288 */
#define ATT_FACTOR 0.08838834764831845f  /* 0.5/sqrt(32) */

typedef __attribute__((ext_vector_type(8))) short short8;   // 8 bf16 = 4 VGPR
typedef __attribute__((ext_vector_type(4))) float floatx4;  // MFMA C/D frag

__device__ __forceinline__ ushort f2bf(float x) {
  union { float f; unsigned u; } v; v.f = x;
  unsigned r = v.u + 0x7fff + ((v.u >> 16) & 1);   // round-to-nearest-even
  return (ushort)(r >> 16);
}

// ---------------- LayerNorm: one block per row of 512 ----------------
__global__ __launch_bounds__(256) void ln_kernel(
    const float* __restrict__ x, float* __restrict__ y, int ystride,
    const float* __restrict__ g, const float* __restrict__ beta)
{
  int row = blockIdx.x;
  int t = threadIdx.x;
  const float* xr = x + (size_t)row * DHID;
  float2 v = ((const float2*)xr)[t];
  float s  = v.x + v.y;
  float ss = v.x*v.x + v.y*v.y;
  #pragma unroll
  for (int off = 32; off > 0; off >>= 1) {
    s  += __shfl_down(s, off);
    ss += __shfl_down(ss, off);
  }
  __shared__ float red[8];
  int w = t >> 6;
  if ((t & 63) == 0) { red[w*2] = s; red[w*2+1] = ss; }
  __syncthreads();
  s  = red[0] + red[2] + red[4] + red[6];
  ss = red[1] + red[3] + red[5] + red[7];
  float mean = s * (1.0f/DHID);
  float var  = ss * (1.0f/DHID) - mean*mean;
  float rstd = rsqrtf(var + 1e-5f);
  float2 gg = ((const float2*)g)[t];
  float2 bb = ((const float2*)beta)[t];
  float2 o;
  o.x = (v.x - mean) * rstd * gg.x + bb.x;
  o.y = (v.y - mean) * rstd * gg.y + bb.y;
  *(float2*)&y[(size_t)row * ystride + 2*t] = o;
}

// ------------- generic SGEMM: C = act(A@W + bias) + resid -------------
// BM=BN=128, BK=8, 256 threads, 8x8 per thread. OUT_BF16: C is ushort*.
template<int ACT, int HAS_BIAS, int HAS_RES, int OUT_BF16>
__global__ __launch_bounds__(256) void gemm_kernel(
    const float* __restrict__ A, const float* __restrict__ W,
    const float* __restrict__ bias, const float* __restrict__ resid,
    float* __restrict__ C, int M, int N, int K)
{
  __shared__ float As[8][128];
  __shared__ float Bs[8][128];
  int t  = threadIdx.x;
  int tx = t & 15, ty = t >> 4;
  int row0 = blockIdx.y * 128, col0 = blockIdx.x * 128;
  int am = t >> 1,  ak = (t & 1) * 4;
  int bk = t >> 5,  bn = (t & 31) * 4;
  const float* Ap = A + (size_t)(row0 + am) * K + ak;
  const float* Wp = W + (size_t)bk * N + col0 + bn;
  float acc[8][8] = {};
  for (int k0 = 0; k0 < K; k0 += 8) {
    float4 av = *(const float4*)Ap; Ap += 8;
    float4 bv = *(const float4*)Wp; Wp += (size_t)8 * N;
    __syncthreads();
    As[ak+0][am] = av.x; As[ak+1][am] = av.y;
    As[ak+2][am] = av.z; As[ak+3][am] = av.w;
    *(float4*)&Bs[bk][bn] = bv;
    __syncthreads();
    #pragma unroll
    for (int kk = 0; kk < 8; kk++) {
      float4 a0 = *(const float4*)&As[kk][ty*8];
      float4 a1 = *(const float4*)&As[kk][ty*8+4];
      float4 b0 = *(const float4*)&Bs[kk][tx*8];
      float4 b1 = *(const float4*)&Bs[kk][tx*8+4];
      float ar[8] = {a0.x,a0.y,a0.z,a0.w,a1.x,a1.y,a1.z,a1.w};
      float br[8] = {b0.x,b0.y,b0.z,b0.w,b1.x,b1.y,b1.z,b1.w};
      #pragma unroll
      for (int i = 0; i < 8; i++)
        #pragma unroll
        for (int j = 0; j < 8; j++)
          acc[i][j] += ar[i]*br[j];
    }
  }
  #pragma unroll
  for (int i = 0; i < 8; i++) {
    int r = row0 + ty*8 + i;
    #pragma unroll
    for (int j4 = 0; j4 < 2; j4++) {
      int c = col0 + tx*8 + j4*4;
      float4 o = { acc[i][j4*4+0], acc[i][j4*4+1], acc[i][j4*4+2], acc[i][j4*4+3] };
      if constexpr (HAS_BIAS) {
        o.x += bias[c]; o.y += bias[c+1]; o.z += bias[c+2]; o.w += bias[c+3];
      }
      if constexpr (ACT == 1) {  // SiLU
        o.x = o.x / (1.f + __expf(-o.x));
        o.y = o.y / (1.f + __expf(-o.y));
        o.z = o.z / (1.f + __expf(-o.z));
        o.w = o.w / (1.f + __expf(-o.w));
      }
      if constexpr (HAS_RES) {
        float4 rv = *(const float4*)&resid[(size_t)r*N + c];
        o.x += rv.x; o.y += rv.y; o.z += rv.z; o.w += rv.w;
      }
      if constexpr (OUT_BF16) {
        ushort* Cu = (ushort*)C;
        ushort4 u = { f2bf(o.x), f2bf(o.y), f2bf(o.z), f2bf(o.w) };
        *(ushort4*)&Cu[(size_t)r*N + c] = u;
      } else {
        *(float4*)&C[(size_t)r*N + c] = o;
      }
    }
  }
}

// ------------- fused bias: Bc[b][n][m] = mask ? Db+Rb : -1e30 -------------
__global__ __launch_bounds__(256) void bias_kernel(
    const float* __restrict__ Db, const float* __restrict__ Rb,
    const int* __restrict__ Mask, float* __restrict__ Bc)
{
  int idx = blockIdx.x*256 + threadIdx.x;   // < 4M
  int b = idx >> 20;
  int m = idx & 1023;
  Bc[idx] = Mask[b*NSEQ + m] ? (Db[idx] + Rb[idx]) : -1e30f;
}

// ------- V_attn transpose -> bf16 Vt[b][h][d(128)][n(1024)] -------
// d<32 from Hv (Hn@Wv), d>=32 from Vvr (V@Wvv) component (d-32)/32.
__global__ __launch_bounds__(256) void vtrans_kernel(
    const float* __restrict__ Hv, const float* __restrict__ Vvr, ushort* __restrict__ Vt)
{
  __shared__ float Ts[64][33];
  int t = threadIdx.x;
  int bh = blockIdx.z;          // b*16+h
  int b = bh >> 4, h = bh & 15;
  int dt = blockIdx.y;          // 0..3 -> d0
  int nt = blockIdx.x;          // 0..15 -> n0
  int d0 = dt*32, n0 = nt*64;
  #pragma unroll
  for (int i = 0; i < 2; i++) {
    int nl = (t >> 3) + i*32;
    int c4 = (t & 7)*4;
    const float* src;
    if (dt == 0) src = &Hv[(size_t)(b*NSEQ + n0 + nl)*512 + h*32 + c4];
    else { int c = dt - 1; src = &Vvr[((size_t)(b*NSEQ + n0 + nl)*3 + c)*512 + h*32 + c4]; }
    float4 v = *(const float4*)src;
    Ts[nl][c4] = v.x; Ts[nl][c4+1] = v.y; Ts[nl][c4+2] = v.z; Ts[nl][c4+3] = v.w;
  }
  __syncthreads();
  int dl = t >> 3;              // 0..31
  int n8 = (t & 7)*8;
  ushort u[8];
  #pragma unroll
  for (int k = 0; k < 8; k++) u[k] = f2bf(Ts[n8+k][dl]);
  size_t ob = ((size_t)bh*128 + d0 + dl)*NSEQ + n0 + n8;
  ushort4 u0 = {u[0],u[1],u[2],u[3]}, u1 = {u[4],u[5],u[6],u[7]};
  *(ushort4*)&Vt[ob]     = u0;
  *(ushort4*)&Vt[ob + 4] = u1;
}

// ------------- bf16 MFMA flash attention -------------
// grid (qtile 16, head 16, batch 4); 256 thr = 4 waves; 64 Q rows/block, 16/wave.
// Q,K: bf16 [b][n][h*128+d] (stride 2048). Vt: bf16 [b][h][d][n]. Bc: fp32 [b][n][m].
// Out: fp32 [(b*N+n)*16 + h]*128 + d  (same layout the pack kernels expect).
__global__ __launch_bounds__(256) void attn_mfma_kernel(
    const ushort* __restrict__ Q, const ushort* __restrict__ K,
    const ushort* __restrict__ Vt, const float* __restrict__ Bc,
    float* __restrict__ Out)
{
  __shared__ union {
    ushort q[64][136];                                  // Q staging (transient)
    struct { ushort k[32][136]; ushort v[128][40]; } kv; // K/V tiles (steady)
  } S;
  __shared__ ushort Ps[4][16][40];                       // per-wave P (bf16)

  int t = threadIdx.x;
  int w = t >> 6, lane = t & 63;
  int q16 = lane & 15, quad = lane >> 4;
  int qt = blockIdx.x, h = blockIdx.y, b = blockIdx.z;
  int q0 = qt * 64;

  // stage Q tile 64x128 bf16
  #pragma unroll
  for (int i = 0; i < 4; i++) {
    int f = t + i*256;
    int r = f >> 4, c8 = f & 15;
    *(float4*)&S.q[r][c8*8] =
        *(const float4*)&Q[(size_t)(b*NSEQ + q0 + r)*2048 + h*128 + c8*8];
  }
  __syncthreads();
  short8 qf[4];
  #pragma unroll
  for (int c = 0; c < 4; c++)
    qf[c] = *(const short8*)&S.q[w*16 + q16][c*32 + quad*8];

  floatx4 o[8];
  #pragma unroll
  for (int i = 0; i < 8; i++) o[i] = (floatx4){0.f,0.f,0.f,0.f};
  float m_i[4] = {-1e30f,-1e30f,-1e30f,-1e30f};
  float l_i[4] = {0.f,0.f,0.f,0.f};
  const float* bias_base = Bc + (size_t)(b*NSEQ + q0 + w*16)*NSEQ;

  for (int m0 = 0; m0 < NSEQ; m0 += 32) {
    __syncthreads();   // prev tile fully consumed (also covers qf loads, iter 0)
    #pragma unroll
    for (int i = 0; i < 2; i++) {
      int f = t + i*256;
      int r = f >> 4, c8 = f & 15;
      *(float4*)&S.kv.k[r][c8*8] =
          *(const float4*)&K[(size_t)(b*NSEQ + m0 + r)*2048 + h*128 + c8*8];
    }
    #pragma unroll
    for (int i = 0; i < 2; i++) {
      int f = t + i*256;
      int d = f >> 2, g = f & 3;
      *(float4*)&S.kv.v[d][g*8] =
          *(const float4*)&Vt[((size_t)(b*NHEADS + h)*128 + d)*NSEQ + m0 + g*8];
    }
    __syncthreads();

    // S = Q K^T : two 16x16 key tiles, K-dim 128 = 4 chunks of 32
    floatx4 s0 = (floatx4){0.f,0.f,0.f,0.f};
    floatx4 s1 = (floatx4){0.f,0.f,0.f,0.f};
    #pragma unroll
    for (int c = 0; c < 4; c++) {
      short8 k0 = *(const short8*)&S.kv.k[q16][c*32 + quad*8];
      short8 k1 = *(const short8*)&S.kv.k[q16 + 16][c*32 + quad*8];
      s0 = __builtin_amdgcn_mfma_f32_16x16x32_bf16(qf[c], k0, s0, 0, 0, 0);
      s1 = __builtin_amdgcn_mfma_f32_16x16x32_bf16(qf[c], k1, s1, 0, 0, 0);
    }
    // bias + online softmax (row = quad*4+i, col = lane&15)
    #pragma unroll
    for (int i = 0; i < 4; i++) {
      int row = quad*4 + i;
      const float* bp = bias_base + (size_t)row*NSEQ + m0 + q16;
      float v0 = s0[i]*ATT_FACTOR + bp[0];
      float v1 = s1[i]*ATT_FACTOR + bp[16];
      float m = fmaxf(v0, v1);
      m = fmaxf(m, __shfl_xor(m, 1));
      m = fmaxf(m, __shfl_xor(m, 2));
      m = fmaxf(m, __shfl_xor(m, 4));
      m = fmaxf(m, __shfl_xor(m, 8));
      float mn = fmaxf(m_i[i], m);
      float alpha = __expf(m_i[i] - mn);
      m_i[i] = mn;
      float p0 = __expf(v0 - mn);
      float p1 = __expf(v1 - mn);
      float ps = p0 + p1;
      ps += __shfl_xor(ps, 1); ps += __shfl_xor(ps, 2);
      ps += __shfl_xor(ps, 4); ps += __shfl_xor(ps, 8);
      l_i[i] = l_i[i]*alpha + ps;
      Ps[w][row][q16]      = f2bf(p0);
      Ps[w][row][16 + q16] = f2bf(p1);
      #pragma unroll
      for (int tt = 0; tt < 8; tt++) o[tt][i] *= alpha;
    }
    // P(16x32) @ V(32x128): A-frag from per-wave LDS (wave-synchronous, no barrier)
    short8 pf = *(const short8*)&Ps[w][q16][quad*8];
    #pragma unroll
    for (int tt = 0; tt < 8; tt++) {
      short8 vf = *(const short8*)&S.kv.v[tt*16 + q16][quad*8];
      o[tt] = __builtin_amdgcn_mfma_f32_16x16x32_bf16(pf, vf, o[tt], 0, 0, 0);
    }
  }
  #pragma unroll
  for (int i = 0; i < 4; i++) {
    float inv = 1.0f / l_i[i];
    int grow = b*NSEQ + q0 + w*16 + quad*4 + i;
    size_t ob = ((size_t)grow*NHEADS + h)*128;
    #pragma unroll
    for (int tt = 0; tt < 8; tt++)
      Out[ob + tt*16 + q16] = o[tt][i] * inv;
  }
}

// ------------- unpack attention result into H_res / V_res -------------
__global__ __launch_bounds__(256) void pack_hres_kernel(
    const float* __restrict__ RES, float* __restrict__ HRES)
{
  int idx = blockIdx.x*256 + threadIdx.x;   // < ROWS*512
  int row = idx >> 9;
  int col = idx & 511;
  int h = col >> 5, j = col & 31;
  HRES[idx] = RES[(size_t)(row*16 + h)*128 + j];
}

__global__ __launch_bounds__(256) void pack_vres_kernel(
    const float* __restrict__ RES, float* __restrict__ VRES)
{
  int idx = blockIdx.x*256 + threadIdx.x;   // < VROWS*512
  int r3 = idx >> 9;
  int col = idx & 511;
  int h = col >> 5, j = col & 31;
  int row = r3 / 3, c = r3 - row*3;
  VRES[idx] = RES[(size_t)(row*16 + h)*128 + 32 + c*32 + j];
}

// ------------- scaler second half: ||V1||_2 over the 3 axis -------------
__global__ __launch_bounds__(256) void vnorm_kernel(
    const float* __restrict__ VP, float* __restrict__ SC)
{
  int idx = blockIdx.x*256 + threadIdx.x;   // < ROWS*512
  int row = idx >> 9;
  int d = idx & 511;
  const float* p = VP + (size_t)row*3072 + d;
  float a = p[0], b = p[1024], c = p[2048];
  SC[(size_t)row*1024 + 512 + d] = sqrtf(a*a + b*b + c*c);
}

// ------------- final combines -------------
__global__ __launch_bounds__(256) void addh_kernel(
    const float* __restrict__ HH, float* __restrict__ Hout)
{
  int idx = blockIdx.x*256 + threadIdx.x;   // < ROWS*512
  int row = idx >> 9;
  int d = idx & 511;
  Hout[idx] += HH[(size_t)row*1024 + d];
}

__global__ __launch_bounds__(256) void fmav_kernel(
    const float* __restrict__ HH, const float* __restrict__ VP, float* __restrict__ Vout)
{
  int idx = blockIdx.x*256 + threadIdx.x;   // < VROWS*512
  int r3 = idx >> 9;
  int d = idx & 511;
  int row = r3 / 3;
  Vout[idx] += HH[(size_t)row*1024 + 512 + d] * VP[(size_t)r3*1024 + 512 + d];
}

extern "C" void kernel_launch(void* const* d_in, const int* in_sizes, int n_in,
                              void* d_out, int out_size, void* d_ws, size_t ws_size,
                              hipStream_t stream)
{
  const float* H    = (const float*)d_in[0];
  const float* V    = (const float*)d_in[1];
  const float* Db   = (const float*)d_in[2];
  const float* Rb   = (const float*)d_in[3];
  const int*   Mask = (const int*)d_in[4];
  const float* g1   = (const float*)d_in[5];
  const float* be1  = (const float*)d_in[6];
  const float* Wq   = (const float*)d_in[7];
  const float* bq   = (const float*)d_in[8];
  const float* Wk   = (const float*)d_in[9];
  const float* bkk  = (const float*)d_in[10];
  const float* Wv   = (const float*)d_in[11];
  const float* bv   = (const float*)d_in[12];
  const float* Wvv  = (const float*)d_in[13];
  const float* Wo   = (const float*)d_in[14];
  const float* bo   = (const float*)d_in[15];
  const float* Wvo  = (const float*)d_in[16];
  const float* g2   = (const float*)d_in[17];
  const float* be2  = (const float*)d_in[18];
  const float* Wlv  = (const float*)d_in[19];
  const float* W1   = (const float*)d_in[20];
  const float* b1f  = (const float*)d_in[21];
  const float* W2   = (const float*)d_in[22];
  const float* b2f  = (const float*)d_in[23];

  float* Hout = (float*)d_out;                  // 4096 x 512
  float* Vout = Hout + (size_t)ROWS*DHID;       // 12288 x 512

  char* w = (char*)d_ws;
  const size_t MB = 1024*1024;
  // phase 1
  float*  HN  = (float*)(w + 0);         //  8MB
  ushort* Qbf = (ushort*)(w + 8*MB);     // 16MB  Q bf16
  ushort* Kbf = (ushort*)(w + 24*MB);    // 16MB  K bf16
  float*  HVt = (float*)(w + 40*MB);     //  8MB  Hn@Wv fp32
  float*  VVr = (float*)(w + 48*MB);     // 24MB  V@Wvv fp32
  ushort* Vtb = (ushort*)(w + 72*MB);    // 16MB  V_attn^T bf16
  float*  Bc  = (float*)(w + 88*MB);     // 16MB  fused bias
  float*  RES = (float*)(w + 104*MB);    // 32MB  attention out
  // phase 2 (aliases dead phase-1 regions; stream order guarantees safety)
  float* HRES = (float*)(w + 0);         //  8MB
  float* VRES = (float*)(w + 8*MB);      // 24MB
  float* VP   = (float*)(w + 0);         // 48MB
  float* SC   = (float*)(w + 48*MB);     // 16MB
  float* S1   = (float*)(w + 64*MB);     // 32MB
  float* HHb  = (float*)(w + 96*MB);     // 16MB

  dim3 blk(256);

  ln_kernel<<<ROWS, blk, 0, stream>>>(H, HN, DHID, g1, be1);

  gemm_kernel<0,1,0,1><<<dim3(16, 32), blk, 0, stream>>>(HN, Wq, bq,  nullptr, (float*)Qbf, 4096, 2048, 512);
  gemm_kernel<0,1,0,1><<<dim3(16, 32), blk, 0, stream>>>(HN, Wk, bkk, nullptr, (float*)Kbf, 4096, 2048, 512);
  gemm_kernel<0,1,0,0><<<dim3(4,  32), blk, 0, stream>>>(HN, Wv, bv,  nullptr, HVt, 4096, 512,  512);
  gemm_kernel<0,0,0,0><<<dim3(4,  96), blk, 0, stream>>>(V,  Wvv, nullptr, nullptr, VVr, 12288, 512, 512);

  bias_kernel<<<(NBATCH*NSEQ*NSEQ)/256, blk, 0, stream>>>(Db, Rb, Mask, Bc);
  vtrans_kernel<<<dim3(16, 4, 64), blk, 0, stream>>>(HVt, VVr, Vtb);

  attn_mfma_kernel<<<dim3(16, 16, 4), blk, 0, stream>>>(Qbf, Kbf, Vtb, Bc, RES);

  pack_hres_kernel<<<(ROWS*DHID)/256,  blk, 0, stream>>>(RES, HRES);
  pack_vres_kernel<<<(VROWS*DHID)/256, blk, 0, stream>>>(RES, VRES);

  gemm_kernel<0,1,1,0><<<dim3(4, 32), blk, 0, stream>>>(HRES, Wo,  bo, H, Hout, 4096, 512, 512);
  gemm_kernel<0,0,1,0><<<dim3(4, 96), blk, 0, stream>>>(VRES, Wvo, nullptr, V, Vout, 12288, 512, 512);

  ln_kernel<<<ROWS, blk, 0, stream>>>(Hout, SC, 1024, g2, be2);
  gemm_kernel<0,0,0,0><<<dim3(8, 96), blk, 0, stream>>>(Vout, Wlv, nullptr, nullptr, VP, 12288, 1024, 512);
  vnorm_kernel<<<(ROWS*DHID)/256, blk, 0, stream>>>(VP, SC);

  gemm_kernel<1,1,0,0><<<dim3(16, 32), blk, 0, stream>>>(SC, W1, b1f, nullptr, S1,  4096, 2048, 1024);
  gemm_kernel<0,1,0,0><<<dim3(8,  32), blk, 0, stream>>>(S1, W2, b2f, nullptr, HHb, 4096, 1024, 2048);

  addh_kernel<<<(ROWS*DHID)/256,  blk, 0, stream>>>(HHb, Hout);
  fmav_kernel<<<(VROWS*DHID)/256, blk, 0, stream>>>(HHb, VP, Vout);
}

// Round 4
// 606.759 us; speedup vs baseline: 12.0133x; 2.7230x over previous
//
#include <hip/hip_runtime.h>
#include <math.h>

#define NBATCH 4
#define NSEQ   1024
#define DHID   512
#define NHEADS 16
#define ROWS   (NBATCH*NSEQ)   /* 4096  */
#define VROWS  (ROWS*3)        /* 12288 */
#define ATT_FACTOR 0.08838834764831845f  /* 0.5/sqrt(32) */

typedef __attribute__((ext_vector_type(8))) short short8;   // 8 bf16 = 4 VGPR
typedef __attribute__((ext_vector_type(4))) float floatx4;  // MFMA C/D frag

__device__ __forceinline__ ushort f2bf(float x) {
  union { float f; unsigned u; } v; v.f = x;
  unsigned r = v.u + 0x7fff + ((v.u >> 16) & 1);   // round-to-nearest-even
  return (ushort)(r >> 16);
}

// ---------------- LayerNorm: one block per row of 512 ----------------
// OBF=1: y is bf16 (ushort*), else fp32. ystride in elements.
template<int OBF>
__global__ __launch_bounds__(256) void ln_kernel(
    const float* __restrict__ x, void* __restrict__ y, int ystride,
    const float* __restrict__ g, const float* __restrict__ beta)
{
  int row = blockIdx.x;
  int t = threadIdx.x;
  const float* xr = x + (size_t)row * DHID;
  float2 v = ((const float2*)xr)[t];
  float s  = v.x + v.y;
  float ss = v.x*v.x + v.y*v.y;
  #pragma unroll
  for (int off = 32; off > 0; off >>= 1) {
    s  += __shfl_down(s, off);
    ss += __shfl_down(ss, off);
  }
  __shared__ float red[8];
  int w = t >> 6;
  if ((t & 63) == 0) { red[w*2] = s; red[w*2+1] = ss; }
  __syncthreads();
  s  = red[0] + red[2] + red[4] + red[6];
  ss = red[1] + red[3] + red[5] + red[7];
  float mean = s * (1.0f/DHID);
  float var  = ss * (1.0f/DHID) - mean*mean;
  float rstd = rsqrtf(var + 1e-5f);
  float2 gg = ((const float2*)g)[t];
  float2 bb = ((const float2*)beta)[t];
  float2 o;
  o.x = (v.x - mean) * rstd * gg.x + bb.x;
  o.y = (v.y - mean) * rstd * gg.y + bb.y;
  if constexpr (OBF) {
    ushort2 u = { f2bf(o.x), f2bf(o.y) };
    *(ushort2*)&((ushort*)y)[(size_t)row * ystride + 2*t] = u;
  } else {
    *(float2*)&((float*)y)[(size_t)row * ystride + 2*t] = o;
  }
}

// ---- weight prep: W fp32 [K][N]  ->  Wt bf16 [N][K], 64x64 tiles ----
__global__ __launch_bounds__(256) void wtrans_kernel(
    const float* __restrict__ W, ushort* __restrict__ Wt, int K, int N)
{
  __shared__ float Ts[64][65];
  int t = threadIdx.x;
  int k0 = blockIdx.y*64, n0 = blockIdx.x*64;
  #pragma unroll
  for (int p = 0; p < 4; p++) {
    int f = p*256 + t;
    int r = f >> 4, c = (f & 15)*4;
    float4 v = *(const float4*)&W[(size_t)(k0+r)*N + n0 + c];
    Ts[r][c] = v.x; Ts[r][c+1] = v.y; Ts[r][c+2] = v.z; Ts[r][c+3] = v.w;
  }
  __syncthreads();
  #pragma unroll
  for (int p = 0; p < 2; p++) {
    int gidx = p*256 + t;
    int nr = gidx >> 3, kc = (gidx & 7)*8;
    ushort u[8];
    #pragma unroll
    for (int x = 0; x < 8; x++) u[x] = f2bf(Ts[kc+x][nr]);
    ushort4 a = {u[0],u[1],u[2],u[3]}, b4 = {u[4],u[5],u[6],u[7]};
    *(ushort4*)&Wt[(size_t)(n0+nr)*K + k0 + kc]     = a;
    *(ushort4*)&Wt[(size_t)(n0+nr)*K + k0 + kc + 4] = b4;
  }
}

// ---- flat fp32 -> bf16 convert (4 elements/thread) ----
__global__ __launch_bounds__(256) void conv_bf16_kernel(
    const float* __restrict__ x, ushort* __restrict__ y)
{
  int i = blockIdx.x*256 + threadIdx.x;
  float4 v = ((const float4*)x)[i];
  ushort4 u = { f2bf(v.x), f2bf(v.y), f2bf(v.z), f2bf(v.w) };
  ((ushort4*)y)[i] = u;
}

// ------------- bf16 MFMA GEMM: C = act(A@W + bias) + resid -------------
// A: bf16 [M][K]; Bt: bf16 [N][K] (pre-transposed weights); 128x128 tile,
// BK=32, 4 waves each 64x64 (4x4 mfma_f32_16x16x32_bf16), fp32 accum.
template<int ACT, int HAS_BIAS, int HAS_RES, int OUT_BF16, int DUAL>
__global__ __launch_bounds__(256) void gemm_mfma_kernel(
    const ushort* __restrict__ A, const ushort* __restrict__ Bt,
    const float* __restrict__ bias, const float* __restrict__ resid,
    void* __restrict__ Cv, ushort* __restrict__ C2,
    int M, int N, int K)
{
  __shared__ ushort As[128*32];   // [m][k] 8 KB
  __shared__ ushort Bs[128*32];   // [n][k] 8 KB
  int t = threadIdx.x;
  int w = t >> 6, lane = t & 63;
  int q16 = lane & 15, quad = lane >> 4;
  int m0 = blockIdx.y * 128, n0 = blockIdx.x * 128;
  int wm = (w & 1) * 64, wn = (w >> 1) * 64;

  int r0 = t >> 2;            // 0..63
  int c0 = (t & 3) * 8;       // 0,8,16,24
  const ushort* Ag = A  + (size_t)(m0 + r0) * K + c0;
  const ushort* Bg = Bt + (size_t)(n0 + r0) * K + c0;

  floatx4 acc[4][4];
  #pragma unroll
  for (int i = 0; i < 4; i++)
    #pragma unroll
    for (int j = 0; j < 4; j++) acc[i][j] = (floatx4){0.f,0.f,0.f,0.f};

  for (int k0 = 0; k0 < K; k0 += 32) {
    float4 av0 = *(const float4*)(Ag + k0);
    float4 av1 = *(const float4*)(Ag + (size_t)64*K + k0);
    float4 bv0 = *(const float4*)(Bg + k0);
    float4 bv1 = *(const float4*)(Bg + (size_t)64*K + k0);
    __syncthreads();
    *(float4*)&As[r0*32 + c0]        = av0;
    *(float4*)&As[(r0 + 64)*32 + c0] = av1;
    *(float4*)&Bs[r0*32 + c0]        = bv0;
    *(float4*)&Bs[(r0 + 64)*32 + c0] = bv1;
    __syncthreads();
    short8 af[4], bf[4];
    #pragma unroll
    for (int i = 0; i < 4; i++) {
      af[i] = *(const short8*)&As[(wm + i*16 + q16)*32 + quad*8];
      bf[i] = *(const short8*)&Bs[(wn + i*16 + q16)*32 + quad*8];
    }
    #pragma unroll
    for (int i = 0; i < 4; i++)
      #pragma unroll
      for (int j = 0; j < 4; j++)
        acc[i][j] = __builtin_amdgcn_mfma_f32_16x16x32_bf16(af[i], bf[j], acc[i][j], 0, 0, 0);
  }

  float* Cf = (float*)Cv;
  ushort* Cu = (ushort*)Cv;
  float bj[4];
  #pragma unroll
  for (int j = 0; j < 4; j++)
    bj[j] = HAS_BIAS ? bias[n0 + wn + j*16 + q16] : 0.f;
  #pragma unroll
  for (int i = 0; i < 4; i++) {
    #pragma unroll
    for (int r = 0; r < 4; r++) {
      int row = m0 + wm + i*16 + quad*4 + r;
      size_t base = (size_t)row * N;
      #pragma unroll
      for (int j = 0; j < 4; j++) {
        int col = n0 + wn + j*16 + q16;
        float v = acc[i][j][r] + bj[j];
        if constexpr (ACT == 1) v = v / (1.f + __expf(-v));
        if constexpr (HAS_RES) v += resid[base + col];
        if constexpr (OUT_BF16) Cu[base + col] = f2bf(v);
        else                    Cf[base + col] = v;
        if constexpr (DUAL) C2[base + col] = f2bf(v);
      }
    }
  }
}

// ------------- fused bias: Bc[b][n][m] = mask ? Db+Rb : -1e30 -------------
__global__ __launch_bounds__(256) void bias_kernel(
    const float* __restrict__ Db, const float* __restrict__ Rb,
    const int* __restrict__ Mask, float* __restrict__ Bc)
{
  int idx = blockIdx.x*256 + threadIdx.x;   // < 4M
  int b = idx >> 20;
  int m = idx & 1023;
  Bc[idx] = Mask[b*NSEQ + m] ? (Db[idx] + Rb[idx]) : -1e30f;
}

// ------- V_attn transpose -> bf16 Vt[b][h][d(128)][n(1024)] -------
__global__ __launch_bounds__(256) void vtrans_kernel(
    const float* __restrict__ Hv, const float* __restrict__ Vvr, ushort* __restrict__ Vt)
{
  __shared__ float Ts[64][33];
  int t = threadIdx.x;
  int bh = blockIdx.z;          // b*16+h
  int b = bh >> 4, h = bh & 15;
  int dt = blockIdx.y;          // 0..3 -> d0
  int nt = blockIdx.x;          // 0..15 -> n0
  int d0 = dt*32, n0 = nt*64;
  #pragma unroll
  for (int i = 0; i < 2; i++) {
    int nl = (t >> 3) + i*32;
    int c4 = (t & 7)*4;
    const float* src;
    if (dt == 0) src = &Hv[(size_t)(b*NSEQ + n0 + nl)*512 + h*32 + c4];
    else { int c = dt - 1; src = &Vvr[((size_t)(b*NSEQ + n0 + nl)*3 + c)*512 + h*32 + c4]; }
    float4 v = *(const float4*)src;
    Ts[nl][c4] = v.x; Ts[nl][c4+1] = v.y; Ts[nl][c4+2] = v.z; Ts[nl][c4+3] = v.w;
  }
  __syncthreads();
  int dl = t >> 3;              // 0..31
  int n8 = (t & 7)*8;
  ushort u[8];
  #pragma unroll
  for (int k = 0; k < 8; k++) u[k] = f2bf(Ts[n8+k][dl]);
  size_t ob = ((size_t)bh*128 + d0 + dl)*NSEQ + n0 + n8;
  ushort4 u0 = {u[0],u[1],u[2],u[3]}, u1 = {u[4],u[5],u[6],u[7]};
  *(ushort4*)&Vt[ob]     = u0;
  *(ushort4*)&Vt[ob + 4] = u1;
}

// ------------- bf16 MFMA flash attention (verified R3) -------------
__global__ __launch_bounds__(256) void attn_mfma_kernel(
    const ushort* __restrict__ Q, const ushort* __restrict__ K,
    const ushort* __restrict__ Vt, const float* __restrict__ Bc,
    float* __restrict__ Out)
{
  __shared__ union {
    ushort q[64][136];
    struct { ushort k[32][136]; ushort v[128][40]; } kv;
  } S;
  __shared__ ushort Ps[4][16][40];

  int t = threadIdx.x;
  int w = t >> 6, lane = t & 63;
  int q16 = lane & 15, quad = lane >> 4;
  int qt = blockIdx.x, h = blockIdx.y, b = blockIdx.z;
  int q0 = qt * 64;

  #pragma unroll
  for (int i = 0; i < 4; i++) {
    int f = t + i*256;
    int r = f >> 4, c8 = f & 15;
    *(float4*)&S.q[r][c8*8] =
        *(const float4*)&Q[(size_t)(b*NSEQ + q0 + r)*2048 + h*128 + c8*8];
  }
  __syncthreads();
  short8 qf[4];
  #pragma unroll
  for (int c = 0; c < 4; c++)
    qf[c] = *(const short8*)&S.q[w*16 + q16][c*32 + quad*8];

  floatx4 o[8];
  #pragma unroll
  for (int i = 0; i < 8; i++) o[i] = (floatx4){0.f,0.f,0.f,0.f};
  float m_i[4] = {-1e30f,-1e30f,-1e30f,-1e30f};
  float l_i[4] = {0.f,0.f,0.f,0.f};
  const float* bias_base = Bc + (size_t)(b*NSEQ + q0 + w*16)*NSEQ;

  for (int m0 = 0; m0 < NSEQ; m0 += 32) {
    __syncthreads();
    #pragma unroll
    for (int i = 0; i < 2; i++) {
      int f = t + i*256;
      int r = f >> 4, c8 = f & 15;
      *(float4*)&S.kv.k[r][c8*8] =
          *(const float4*)&K[(size_t)(b*NSEQ + m0 + r)*2048 + h*128 + c8*8];
    }
    #pragma unroll
    for (int i = 0; i < 2; i++) {
      int f = t + i*256;
      int d = f >> 2, g = f & 3;
      *(float4*)&S.kv.v[d][g*8] =
          *(const float4*)&Vt[((size_t)(b*NHEADS + h)*128 + d)*NSEQ + m0 + g*8];
    }
    __syncthreads();

    floatx4 s0 = (floatx4){0.f,0.f,0.f,0.f};
    floatx4 s1 = (floatx4){0.f,0.f,0.f,0.f};
    #pragma unroll
    for (int c = 0; c < 4; c++) {
      short8 k0 = *(const short8*)&S.kv.k[q16][c*32 + quad*8];
      short8 k1 = *(const short8*)&S.kv.k[q16 + 16][c*32 + quad*8];
      s0 = __builtin_amdgcn_mfma_f32_16x16x32_bf16(qf[c], k0, s0, 0, 0, 0);
      s1 = __builtin_amdgcn_mfma_f32_16x16x32_bf16(qf[c], k1, s1, 0, 0, 0);
    }
    #pragma unroll
    for (int i = 0; i < 4; i++) {
      int row = quad*4 + i;
      const float* bp = bias_base + (size_t)row*NSEQ + m0 + q16;
      float v0 = s0[i]*ATT_FACTOR + bp[0];
      float v1 = s1[i]*ATT_FACTOR + bp[16];
      float m = fmaxf(v0, v1);
      m = fmaxf(m, __shfl_xor(m, 1));
      m = fmaxf(m, __shfl_xor(m, 2));
      m = fmaxf(m, __shfl_xor(m, 4));
      m = fmaxf(m, __shfl_xor(m, 8));
      float mn = fmaxf(m_i[i], m);
      float alpha = __expf(m_i[i] - mn);
      m_i[i] = mn;
      float p0 = __expf(v0 - mn);
      float p1 = __expf(v1 - mn);
      float ps = p0 + p1;
      ps += __shfl_xor(ps, 1); ps += __shfl_xor(ps, 2);
      ps += __shfl_xor(ps, 4); ps += __shfl_xor(ps, 8);
      l_i[i] = l_i[i]*alpha + ps;
      Ps[w][row][q16]      = f2bf(p0);
      Ps[w][row][16 + q16] = f2bf(p1);
      #pragma unroll
      for (int tt = 0; tt < 8; tt++) o[tt][i] *= alpha;
    }
    short8 pf = *(const short8*)&Ps[w][q16][quad*8];
    #pragma unroll
    for (int tt = 0; tt < 8; tt++) {
      short8 vf = *(const short8*)&S.kv.v[tt*16 + q16][quad*8];
      o[tt] = __builtin_amdgcn_mfma_f32_16x16x32_bf16(pf, vf, o[tt], 0, 0, 0);
    }
  }
  #pragma unroll
  for (int i = 0; i < 4; i++) {
    float inv = 1.0f / l_i[i];
    int grow = b*NSEQ + q0 + w*16 + quad*4 + i;
    size_t ob = ((size_t)grow*NHEADS + h)*128;
    #pragma unroll
    for (int tt = 0; tt < 8; tt++)
      Out[ob + tt*16 + q16] = o[tt][i] * inv;
  }
}

// ------------- unpack attention result into bf16 H_res / V_res -------------
__global__ __launch_bounds__(256) void pack_hres_kernel(
    const float* __restrict__ RES, ushort* __restrict__ HRES)
{
  int idx = blockIdx.x*256 + threadIdx.x;   // < ROWS*512
  int row = idx >> 9;
  int col = idx & 511;
  int h = col >> 5, j = col & 31;
  HRES[idx] = f2bf(RES[(size_t)(row*16 + h)*128 + j]);
}

__global__ __launch_bounds__(256) void pack_vres_kernel(
    const float* __restrict__ RES, ushort* __restrict__ VRES)
{
  int idx = blockIdx.x*256 + threadIdx.x;   // < VROWS*512
  int r3 = idx >> 9;
  int col = idx & 511;
  int h = col >> 5, j = col & 31;
  int row = r3 / 3, c = r3 - row*3;
  VRES[idx] = f2bf(RES[(size_t)(row*16 + h)*128 + 32 + c*32 + j]);
}

// ------------- scaler second half: ||V1||_2, bf16 out -------------
__global__ __launch_bounds__(256) void vnorm_kernel(
    const float* __restrict__ VP, ushort* __restrict__ SC)
{
  int idx = blockIdx.x*256 + threadIdx.x;   // < ROWS*512
  int row = idx >> 9;
  int d = idx & 511;
  const float* p = VP + (size_t)row*3072 + d;
  float a = p[0], b = p[1024], c = p[2048];
  SC[(size_t)row*1024 + 512 + d] = f2bf(sqrtf(a*a + b*b + c*c));
}

// ------------- final combines -------------
__global__ __launch_bounds__(256) void addh_kernel(
    const float* __restrict__ HH, float* __restrict__ Hout)
{
  int idx = blockIdx.x*256 + threadIdx.x;   // < ROWS*512
  int row = idx >> 9;
  int d = idx & 511;
  Hout[idx] += HH[(size_t)row*1024 + d];
}

__global__ __launch_bounds__(256) void fmav_kernel(
    const float* __restrict__ HH, const float* __restrict__ VP, float* __restrict__ Vout)
{
  int idx = blockIdx.x*256 + threadIdx.x;   // < VROWS*512
  int r3 = idx >> 9;
  int d = idx & 511;
  int row = r3 / 3;
  Vout[idx] += HH[(size_t)row*1024 + 512 + d] * VP[(size_t)r3*1024 + 512 + d];
}

extern "C" void kernel_launch(void* const* d_in, const int* in_sizes, int n_in,
                              void* d_out, int out_size, void* d_ws, size_t ws_size,
                              hipStream_t stream)
{
  const float* H    = (const float*)d_in[0];
  const float* V    = (const float*)d_in[1];
  const float* Db   = (const float*)d_in[2];
  const float* Rb   = (const float*)d_in[3];
  const int*   Mask = (const int*)d_in[4];
  const float* g1   = (const float*)d_in[5];
  const float* be1  = (const float*)d_in[6];
  const float* Wq   = (const float*)d_in[7];
  const float* bq   = (const float*)d_in[8];
  const float* Wk   = (const float*)d_in[9];
  const float* bkk  = (const float*)d_in[10];
  const float* Wv   = (const float*)d_in[11];
  const float* bv   = (const float*)d_in[12];
  const float* Wvv  = (const float*)d_in[13];
  const float* Wo   = (const float*)d_in[14];
  const float* bo   = (const float*)d_in[15];
  const float* Wvo  = (const float*)d_in[16];
  const float* g2   = (const float*)d_in[17];
  const float* be2  = (const float*)d_in[18];
  const float* Wlv  = (const float*)d_in[19];
  const float* W1   = (const float*)d_in[20];
  const float* b1f  = (const float*)d_in[21];
  const float* W2   = (const float*)d_in[22];
  const float* b2f  = (const float*)d_in[23];

  float* Hout = (float*)d_out;                  // 4096 x 512
  float* Vout = Hout + (size_t)ROWS*DHID;       // 12288 x 512

  char* w = (char*)d_ws;
  const size_t MB = 1024*1024;
  const size_t KB = 1024;
  // weights bf16 transposed (live whole launch): 0 - 15.5 MB
  ushort* WqT  = (ushort*)(w + 0);
  ushort* WkT  = (ushort*)(w + 2048*KB);
  ushort* WvT  = (ushort*)(w + 4096*KB);
  ushort* WvvT = (ushort*)(w + 4608*KB);
  ushort* WoT  = (ushort*)(w + 5120*KB);
  ushort* WvoT = (ushort*)(w + 5632*KB);
  ushort* WlvT = (ushort*)(w + 6144*KB);
  ushort* W1T  = (ushort*)(w + 7168*KB);
  ushort* W2T  = (ushort*)(w + 11264*KB);
  // phase 1
  ushort* HNbf = (ushort*)(w + 16*MB);   //  4MB
  ushort* Qbf  = (ushort*)(w + 20*MB);   // 16MB
  ushort* Kbf  = (ushort*)(w + 36*MB);   // 16MB
  float*  HVt  = (float*)(w + 52*MB);    //  8MB
  float*  VVr  = (float*)(w + 60*MB);    // 24MB
  ushort* Vbf  = (ushort*)(w + 84*MB);   // 12MB
  ushort* Vtb  = (ushort*)(w + 96*MB);   // 16MB
  float*  Bc   = (float*)(w + 112*MB);   // 16MB
  float*  RES  = (float*)(w + 52*MB);    // 32MB (reuses HVt/VVr after vtrans)
  // phase 2 (aliases dead phase-1 regions)
  ushort* HRESbf = (ushort*)(w + 16*MB); //  4MB (HNbf dead)
  ushort* VRESbf = (ushort*)(w + 20*MB); // 12MB (Qbf dead after attn)
  ushort* Voutbf = (ushort*)(w + 32*MB); // 12MB (Qbf tail/Kbf dead)
  float*  VP     = (float*)(w + 52*MB);  // 48MB (RES dead after packs, Vtb dead)
  ushort* SCbf   = (ushort*)(w + 100*MB);//  8MB
  ushort* S1bf   = (ushort*)(w + 112*MB);// 16MB (Bc dead after attn)
  float*  HHb    = (float*)(w + 16*MB);  // 16MB (HRESbf/VRESbf dead after Wo/Wvo)

  dim3 blk(256);

  // ---- weight prep ----
  wtrans_kernel<<<dim3(32,  8), blk, 0, stream>>>(Wq,  WqT,  512, 2048);
  wtrans_kernel<<<dim3(32,  8), blk, 0, stream>>>(Wk,  WkT,  512, 2048);
  wtrans_kernel<<<dim3( 8,  8), blk, 0, stream>>>(Wv,  WvT,  512, 512);
  wtrans_kernel<<<dim3( 8,  8), blk, 0, stream>>>(Wvv, WvvT, 512, 512);
  wtrans_kernel<<<dim3( 8,  8), blk, 0, stream>>>(Wo,  WoT,  512, 512);
  wtrans_kernel<<<dim3( 8,  8), blk, 0, stream>>>(Wvo, WvoT, 512, 512);
  wtrans_kernel<<<dim3(16,  8), blk, 0, stream>>>(Wlv, WlvT, 512, 1024);
  wtrans_kernel<<<dim3(32, 16), blk, 0, stream>>>(W1,  W1T, 1024, 2048);
  wtrans_kernel<<<dim3(16, 32), blk, 0, stream>>>(W2,  W2T, 2048, 1024);

  ln_kernel<1><<<ROWS, blk, 0, stream>>>(H, HNbf, DHID, g1, be1);
  conv_bf16_kernel<<<(VROWS*DHID/4)/256, blk, 0, stream>>>(V, Vbf);

  gemm_mfma_kernel<0,1,0,1,0><<<dim3(16, 32), blk, 0, stream>>>(HNbf, WqT, bq,  nullptr, Qbf, nullptr, 4096, 2048, 512);
  gemm_mfma_kernel<0,1,0,1,0><<<dim3(16, 32), blk, 0, stream>>>(HNbf, WkT, bkk, nullptr, Kbf, nullptr, 4096, 2048, 512);
  gemm_mfma_kernel<0,1,0,0,0><<<dim3( 4, 32), blk, 0, stream>>>(HNbf, WvT, bv,  nullptr, HVt, nullptr, 4096, 512, 512);
  gemm_mfma_kernel<0,0,0,0,0><<<dim3( 4, 96), blk, 0, stream>>>(Vbf, WvvT, nullptr, nullptr, VVr, nullptr, 12288, 512, 512);

  bias_kernel<<<(NBATCH*NSEQ*NSEQ)/256, blk, 0, stream>>>(Db, Rb, Mask, Bc);
  vtrans_kernel<<<dim3(16, 4, 64), blk, 0, stream>>>(HVt, VVr, Vtb);

  attn_mfma_kernel<<<dim3(16, 16, 4), blk, 0, stream>>>(Qbf, Kbf, Vtb, Bc, RES);

  pack_hres_kernel<<<(ROWS*DHID)/256,  blk, 0, stream>>>(RES, HRESbf);
  pack_vres_kernel<<<(VROWS*DHID)/256, blk, 0, stream>>>(RES, VRESbf);

  gemm_mfma_kernel<0,1,1,0,0><<<dim3(4, 32), blk, 0, stream>>>(HRESbf, WoT,  bo, H, Hout, nullptr, 4096, 512, 512);
  gemm_mfma_kernel<0,0,1,0,1><<<dim3(4, 96), blk, 0, stream>>>(VRESbf, WvoT, nullptr, V, Vout, Voutbf, 12288, 512, 512);

  ln_kernel<1><<<ROWS, blk, 0, stream>>>(Hout, SCbf, 1024, g2, be2);
  gemm_mfma_kernel<0,0,0,0,0><<<dim3(8, 96), blk, 0, stream>>>(Voutbf, WlvT, nullptr, nullptr, VP, nullptr, 12288, 1024, 512);
  vnorm_kernel<<<(ROWS*DHID)/256, blk, 0, stream>>>(VP, SCbf);

  gemm_mfma_kernel<1,1,0,1,0><<<dim3(16, 32), blk, 0, stream>>>(SCbf, W1T, b1f, nullptr, S1bf, nullptr, 4096, 2048, 1024);
  gemm_mfma_kernel<0,1,0,0,0><<<dim3( 8, 32), blk, 0, stream>>>(S1bf, W2T, b2f, nullptr, HHb, nullptr, 4096, 1024, 2048);

  addh_kernel<<<(ROWS*DHID)/256,  blk, 0, stream>>>(HHb, Hout);
  fmav_kernel<<<(VROWS*DHID)/256, blk, 0, stream>>>(HHb, VP, Vout);
}